// Round 7
// baseline (248.857 us; speedup 1.0000x reference)
//
#include <hip/hip_runtime.h>
#include <hip/hip_bf16.h>
#include <math.h>

#define B    512
#define INU  8
#define IC   1152
#define NU   10
#define US   16
#define JU   160            // NU*US
#define KI   9216           // INU*IC
#define BETAC 1.45f
#define NSPLIT 32
#define KC 288              // KI / NSPLIT; divides IC

typedef __attribute__((ext_vector_type(8))) __bf16 bf16x8;
typedef __attribute__((ext_vector_type(4))) float floatx4;

static __device__ __forceinline__ unsigned short f2bf(float f) {
  unsigned u = __builtin_bit_cast(unsigned, f);
  u = (u + 0x7fffu + ((u >> 16) & 1u)) >> 16;   // RNE
  return (unsigned short)u;
}
static __device__ __forceinline__ float bf2f(unsigned short h) {
  return __builtin_bit_cast(float, ((unsigned)h) << 16);
}
// 8 bf16 * 8 fp32 scale -> 8 bf16 (packed RNE converts)
static __device__ __forceinline__ uint4 scale8(uint4 wv, float4 cA, float4 cB) {
  union { uint4 u; unsigned short s[8]; } in;
  in.u = wv;
  union { uint4 u; __hip_bfloat162 h[4]; } o;
  o.h[0] = __float22bfloat162_rn(make_float2(bf2f(in.s[0]) * cA.x, bf2f(in.s[1]) * cA.y));
  o.h[1] = __float22bfloat162_rn(make_float2(bf2f(in.s[2]) * cA.z, bf2f(in.s[3]) * cA.w));
  o.h[2] = __float22bfloat162_rn(make_float2(bf2f(in.s[4]) * cB.x, bf2f(in.s[5]) * cB.y));
  o.h[3] = __float22bfloat162_rn(make_float2(bf2f(in.s[6]) * cB.z, bf2f(in.s[7]) * cB.w));
  return o.u;
}

// ---------------------------------------------------------------------------
// prep (one-time): blocks [0,1152): x -> xb bf16 [b][ki] + xT bf16 [ki][b]
// (64x64 LDS transpose). blocks [1152,1296): W LDS-tiled -> Wt bf16 [ju][ki]
// (MFMA B layout) + Wr fp32 [ki][ju] (coalesced epilogue). Block 1152 inits
// cT = 1/IC (softmax of zero logits).
// ---------------------------------------------------------------------------
__global__ __launch_bounds__(256) void prep_kernel(
    const float* __restrict__ x, const float* __restrict__ W,
    unsigned short* __restrict__ xb, unsigned short* __restrict__ xT,
    unsigned short* __restrict__ Wt, float* __restrict__ Wr,
    float* __restrict__ cT) {
  __shared__ float ts[32 * 322];    // 41.2 KB (x-part uses first 64*65)
  int id = blockIdx.x;
  int t = threadIdx.x;
  if (id < 1152) {
    int k0 = (id % 144) * 64;
    int b0 = (id / 144) * 64;
#pragma unroll
    for (int r = 0; r < 16; ++r) {
      int idx = t + 256 * r;
      int br = idx >> 6, kc = idx & 63;
      float v = x[(size_t)(b0 + br) * KI + k0 + kc];
      ts[br * 65 + kc] = v;
      xb[(size_t)(b0 + br) * KI + k0 + kc] = f2bf(v);
    }
    __syncthreads();
#pragma unroll
    for (int r = 0; r < 8; ++r) {
      int idx = t + 256 * r;            // 0..2047
      int kr = idx >> 5, bc = (idx & 31) * 2;
      unsigned lo = f2bf(ts[bc * 65 + kr]);
      unsigned hi = f2bf(ts[(bc + 1) * 65 + kr]);
      *(unsigned*)&xT[(size_t)(k0 + kr) * B + b0 + bc] = lo | (hi << 16);
    }
  } else {
    int wid = id - 1152;              // 0..143
    int i0 = (wid >> 2) * 32;         // 36 i-chunks
    int c0 = (wid & 3) * 320;         // 4 c-chunks of W's 1280-wide rows
#pragma unroll
    for (int r = 0; r < 20; ++r) {
      int q = t + 256 * r;            // < 5120 float2
      int il = q / 160, c = (q - il * 160) * 2;
      *(float2*)&ts[il * 322 + c] =
          *(const float2*)&W[(size_t)(i0 + il) * 1280 + c0 + c];
    }
    __syncthreads();
    {
      int il2 = (t & 15) * 2;
      for (int p = (t >> 4); p < 320; p += 16) {
        int c = c0 + p;
        int ju = c >> 3, k = c & 7;
        unsigned lo = f2bf(ts[il2 * 322 + p]);
        unsigned hi = f2bf(ts[(il2 + 1) * 322 + p]);
        *(unsigned*)&Wt[(size_t)ju * KI + k * IC + i0 + il2] = lo | (hi << 16);
      }
    }
    int ju0 = c0 >> 3;
    for (int q = t; q < 8 * 32 * 40; q += 256) {
      int k = q / 1280;
      int il = (q / 40) & 31;
      int jl = q - (q / 40) * 40;
      Wr[((size_t)k * IC + i0 + il) * JU + ju0 + jl] = ts[il * 322 + jl * 8 + k];
    }
    if (id == 1152) {
      for (int q = t; q < IC * NU; q += 256) cT[q] = 1.0f / (float)IC;
    }
  }
}

// ---------------------------------------------------------------------------
// s_gemm (MFMA, fused c-scale from LDS, reg double-buffered):
// sp[y][b][ju] = sum_{ki in chunk y} xb[b,ki] * (Wt[ju,ki] * cT[j, i(ki)])
// Grid: (8 b-tiles of 64, NSPLIT) x 256.
// ---------------------------------------------------------------------------
__global__ __launch_bounds__(256) void s_gemm_mfma(
    const unsigned short* __restrict__ xb, const unsigned short* __restrict__ Wt,
    const float* __restrict__ cT, float* __restrict__ sp) {
  int b0 = blockIdx.x * 64;
  int kbase = blockIdx.y * KC;
  int i0 = kbase % IC;
  int t = threadIdx.x;
  int w = t >> 6, lane = t & 63, col = lane & 15, quad = lane >> 4;
  __shared__ unsigned short xs[64 * 40];    // pad 40: <=2-way (free)
  __shared__ unsigned short ms[160 * 40];
  __shared__ float cs[NU * KC];             // 11.5 KB

  int xrow = t >> 2, xc = (t & 3) * 8;
  int mrow0 = t >> 2, mrow1 = (t + 256) >> 2, mrow2 = (t + 512) >> 2;
  int mc = (t & 3) * 8;
  int j0 = mrow0 >> 4, j1 = mrow1 >> 4, j2 = mrow2 >> 4;

  for (int ch = t; ch < NU * KC; ch += 256) {
    int j = ch / KC;
    cs[ch] = cT[j * IC + i0 + (ch - j * KC)];
  }
  uint4 xv, m0, m1, m2;
  auto prefetch = [&](int k0) {
    xv = *(const uint4*)&xb[(size_t)(b0 + xrow) * KI + k0 + xc];
    m0 = *(const uint4*)&Wt[(size_t)mrow0 * KI + k0 + mc];
    m1 = *(const uint4*)&Wt[(size_t)mrow1 * KI + k0 + mc];
    if (t < 128) m2 = *(const uint4*)&Wt[(size_t)mrow2 * KI + k0 + mc];
  };
  auto commit = [&](int off) {
    *(uint4*)&xs[xrow * 40 + xc] = xv;
    float4 a0 = *(const float4*)&cs[j0 * KC + off + mc];
    float4 a1 = *(const float4*)&cs[j0 * KC + off + mc + 4];
    *(uint4*)&ms[mrow0 * 40 + mc] = scale8(m0, a0, a1);
    float4 b0c = *(const float4*)&cs[j1 * KC + off + mc];
    float4 b1c = *(const float4*)&cs[j1 * KC + off + mc + 4];
    *(uint4*)&ms[mrow1 * 40 + mc] = scale8(m1, b0c, b1c);
    if (t < 128) {
      float4 d0 = *(const float4*)&cs[j2 * KC + off + mc];
      float4 d1 = *(const float4*)&cs[j2 * KC + off + mc + 4];
      *(uint4*)&ms[mrow2 * 40 + mc] = scale8(m2, d0, d1);
    }
  };
  floatx4 acc[10];
#pragma unroll
  for (int jt = 0; jt < 10; ++jt) acc[jt] = (floatx4){0.f, 0.f, 0.f, 0.f};
  prefetch(kbase);
  __syncthreads();   // cs ready
  const int nsteps = KC >> 5;  // 9
  for (int s = 0; s < nsteps; ++s) {
    commit(s * 32);
    __syncthreads();
    if (s + 1 < nsteps) prefetch(kbase + (s + 1) * 32);
    bf16x8 a = *(bf16x8*)&xs[(w * 16 + col) * 40 + quad * 8];
#pragma unroll
    for (int jt = 0; jt < 10; ++jt) {
      bf16x8 bb = *(bf16x8*)&ms[(jt * 16 + col) * 40 + quad * 8];
      acc[jt] = __builtin_amdgcn_mfma_f32_16x16x32_bf16(a, bb, acc[jt], 0, 0, 0);
    }
    __syncthreads();
  }
#pragma unroll
  for (int jt = 0; jt < 10; ++jt)
#pragma unroll
    for (int r = 0; r < 4; ++r) {
      int b = b0 + w * 16 + quad * 4 + r;
      sp[((size_t)blockIdx.y * B + b) * JU + jt * 16 + col] = acc[jt][r];
    }
}

// ---------------------------------------------------------------------------
// squash: s[b][ju] = sum_ks sp; msq over j (axis=1 quirk, faithful);
// v -> vT bf16 [ju][b]; out fp32 on last iter. Block 0 also zeroes bij and
// the ticket for the FOLLOWING b_update (kernel boundary = safe).
// Grid: 512 x 192.
// ---------------------------------------------------------------------------
__global__ __launch_bounds__(192) void squash_kernel(
    const float* __restrict__ sp, unsigned short* __restrict__ vT,
    float* __restrict__ out, float* __restrict__ bij,
    unsigned* __restrict__ ticket) {
  int b = blockIdx.x;
  int t = threadIdx.x;
  if (b == 0) {
    for (int q = t; q < IC * NU; q += 192) bij[q] = 0.0f;
    if (t == 0) ticket[0] = 0u;
  }
  __shared__ float sv[JU];
  __shared__ float fac[US];
  float s = 0.0f;
  if (t < JU) {
#pragma unroll
    for (int k = 0; k < NSPLIT; ++k) s += sp[((size_t)k * B + b) * JU + t];
    sv[t] = s;
  }
  __syncthreads();
  if (t < US) {
    float m = 0.0f;
#pragma unroll
    for (int j = 0; j < NU; ++j) {
      float q = sv[j * US + t];
      m += q * q;
    }
    fac[t] = sqrtf(m) / (BETAC + m);
  }
  __syncthreads();
  if (t < JU) {
    float val = s * fac[t & 15];
    vT[(size_t)t * B + b] = f2bf(val);
    if (out) out[(size_t)b * JU + t] = val;
  }
}

// ---------------------------------------------------------------------------
// b_update (MFMA, dbuf, fused softmax): R[ki,ju] = sum_b xT[ki,b]*vT[ju,b];
// each block atomicAdds its (k,bs) contribution into bij[j][i] (46 KB,
// device-scope coherent). Last-arriving block (ticket rank 287; NO spinning)
// acquires and computes cT[j][i] = softmax_i(bij) -- ~46 KB tail.
// Grid: (144, 2) x 256.
// ---------------------------------------------------------------------------
__global__ __launch_bounds__(256) void b_update_mfma(
    const unsigned short* __restrict__ xT, const unsigned short* __restrict__ vT,
    const float* __restrict__ Wr, float* __restrict__ bij,
    float* __restrict__ cT, unsigned* __restrict__ ticket) {
  int k = blockIdx.x / 18;
  int i0 = (blockIdx.x - k * 18) * 64;
  int bs = blockIdx.y;
  size_t ki0 = (size_t)k * IC + i0;
  int t = threadIdx.x;
  int w = t >> 6, lane = t & 63, col = lane & 15, quad = lane >> 4;
  __shared__ unsigned short xs[64 * 40];
  __shared__ unsigned short vs[160 * 40];
  __shared__ int sflag;
  int xrow = t >> 2, xc = (t & 3) * 8;
  int mrow0 = t >> 2, mrow1 = (t + 256) >> 2, mrow2 = (t + 512) >> 2;
  int mc = (t & 3) * 8;
  uint4 xv, m0, m1, m2;
  auto prefetch = [&](int c0) {
    xv = *(const uint4*)&xT[(ki0 + xrow) * B + c0 + xc];
    m0 = *(const uint4*)&vT[(size_t)mrow0 * B + c0 + mc];
    m1 = *(const uint4*)&vT[(size_t)mrow1 * B + c0 + mc];
    if (t < 128) m2 = *(const uint4*)&vT[(size_t)mrow2 * B + c0 + mc];
  };
  auto commit = [&]() {
    *(uint4*)&xs[xrow * 40 + xc] = xv;
    *(uint4*)&vs[mrow0 * 40 + mc] = m0;
    *(uint4*)&vs[mrow1 * 40 + mc] = m1;
    if (t < 128) *(uint4*)&vs[mrow2 * 40 + mc] = m2;
  };
  floatx4 acc[10];
#pragma unroll
  for (int jt = 0; jt < 10; ++jt) acc[jt] = (floatx4){0.f, 0.f, 0.f, 0.f};
  prefetch(bs * 256);
  for (int s = 0; s < 8; ++s) {
    commit();
    __syncthreads();
    if (s < 7) prefetch(bs * 256 + (s + 1) * 32);
    bf16x8 a = *(bf16x8*)&xs[(w * 16 + col) * 40 + quad * 8];
#pragma unroll
    for (int jt = 0; jt < 10; ++jt) {
      bf16x8 bb = *(bf16x8*)&vs[(jt * 16 + col) * 40 + quad * 8];
      acc[jt] = __builtin_amdgcn_mfma_f32_16x16x32_bf16(a, bb, acc[jt], 0, 0, 0);
    }
    __syncthreads();
  }
#pragma unroll
  for (int jt = 0; jt < 10; ++jt) {
#pragma unroll
    for (int r = 0; r < 4; ++r) {
      int i = i0 + w * 16 + quad * 4 + r;
      float wv = Wr[((size_t)k * IC + i) * JU + jt * 16 + col];
      float pr = wv * acc[jt][r];
      pr += __shfl_xor(pr, 1);
      pr += __shfl_xor(pr, 2);
      pr += __shfl_xor(pr, 4);
      pr += __shfl_xor(pr, 8);
      if (col == 0)
        atomicAdd(&bij[jt * IC + i], pr * (1.0f / (float)B));
    }
  }
  // ---- last-block softmax tail (no spinning: single rank check) ----
  __syncthreads();
  if (t == 0) {
    __threadfence();   // release: bij adds ordered before ticket add
    sflag = (atomicAdd(ticket, 1u) == 287u) ? 1 : 0;
  }
  __syncthreads();
  if (sflag) {
    __threadfence();   // acquire: invalidate L1/L2 so bij reads are fresh
    float* fb = (float*)xs;    // 1152 floats (4.6 KB <= 5.1 KB)
    float* red = (float*)vs;   // 256 floats
    for (int j = 0; j < NU; ++j) {
      for (int i = t; i < IC; i += 256) fb[i] = bij[j * IC + i];
      __syncthreads();
      float ml = -1e30f;
      for (int i = t; i < IC; i += 256) ml = fmaxf(ml, fb[i]);
      red[t] = ml;
      __syncthreads();
      for (int o = 128; o > 0; o >>= 1) {
        if (t < o) red[t] = fmaxf(red[t], red[t + o]);
        __syncthreads();
      }
      float mx = red[0];
      __syncthreads();
      float sl = 0.0f;
      for (int i = t; i < IC; i += 256) {
        float e = __expf(fb[i] - mx);
        fb[i] = e;
        sl += e;
      }
      red[t] = sl;
      __syncthreads();
      for (int o = 128; o > 0; o >>= 1) {
        if (t < o) red[t] += red[t + o];
        __syncthreads();
      }
      float inv = 1.0f / red[0];
      __syncthreads();
      for (int i = t; i < IC; i += 256) cT[j * IC + i] = fb[i] * inv;
      __syncthreads();
    }
  }
}

// ---------------------------------------------------------------------------
extern "C" void kernel_launch(void* const* d_in, const int* in_sizes, int n_in,
                              void* d_out, int out_size, void* d_ws,
                              size_t ws_size, hipStream_t stream) {
  const float* x = (const float*)d_in[0];   // (512, 8, 1152)
  const float* W = (const float*)d_in[1];   // (1152, 10, 16, 8)
  float* out = (float*)d_out;               // (512, 10, 16)

  // workspace layout (~39 MB; harness provides ~268 MB)
  char* pws = (char*)d_ws;
  float* cT = (float*)pws;                     pws += (size_t)NU * IC * 4;
  float* bij = (float*)pws;                    pws += (size_t)NU * IC * 4;
  unsigned* ticket = (unsigned*)pws;           pws += 256;
  float* sp = (float*)pws;                     pws += (size_t)NSPLIT * B * JU * 4;
  float* Wr = (float*)pws;                     pws += (size_t)KI * JU * 4;
  unsigned short* xb = (unsigned short*)pws;   pws += (size_t)B * KI * 2;
  unsigned short* xT = (unsigned short*)pws;   pws += (size_t)KI * B * 2;
  unsigned short* Wt = (unsigned short*)pws;   pws += (size_t)JU * KI * 2;
  unsigned short* vT = (unsigned short*)pws;

  prep_kernel<<<1152 + 144, 256, 0, stream>>>(x, W, xb, xT, Wt, Wr, cT);

  for (int it = 0; it < 3; ++it) {
    s_gemm_mfma<<<dim3(8, NSPLIT), 256, 0, stream>>>(xb, Wt, cT, sp);
    squash_kernel<<<B, 192, 0, stream>>>(sp, vT, (it == 2) ? out : nullptr,
                                         bij, ticket);
    if (it < 2) {
      b_update_mfma<<<dim3(144, 2), 256, 0, stream>>>(xT, vT, Wr, bij, cT,
                                                      ticket);
    }
  }
}

// Round 8
// 201.162 us; speedup vs baseline: 1.2371x; 1.2371x over previous
//
#include <hip/hip_runtime.h>
#include <hip/hip_bf16.h>
#include <math.h>

#define B    512
#define INU  8
#define IC   1152
#define NU   10
#define US   16
#define JU   160            // NU*US
#define KI   9216           // INU*IC
#define BETAC 1.45f
#define NSPLIT 32
#define KC 288              // KI / NSPLIT; divides IC

typedef __attribute__((ext_vector_type(8))) __bf16 bf16x8;
typedef __attribute__((ext_vector_type(4))) float floatx4;

static __device__ __forceinline__ unsigned short f2bf(float f) {
  unsigned u = __builtin_bit_cast(unsigned, f);
  u = (u + 0x7fffu + ((u >> 16) & 1u)) >> 16;   // RNE
  return (unsigned short)u;
}
static __device__ __forceinline__ float bf2f(unsigned short h) {
  return __builtin_bit_cast(float, ((unsigned)h) << 16);
}
// 8 bf16 * 8 fp32 scale -> 8 bf16 (packed RNE converts)
static __device__ __forceinline__ uint4 scale8(uint4 wv, float4 cA, float4 cB) {
  union { uint4 u; unsigned short s[8]; } in;
  in.u = wv;
  union { uint4 u; __hip_bfloat162 h[4]; } o;
  o.h[0] = __float22bfloat162_rn(make_float2(bf2f(in.s[0]) * cA.x, bf2f(in.s[1]) * cA.y));
  o.h[1] = __float22bfloat162_rn(make_float2(bf2f(in.s[2]) * cA.z, bf2f(in.s[3]) * cA.w));
  o.h[2] = __float22bfloat162_rn(make_float2(bf2f(in.s[4]) * cB.x, bf2f(in.s[5]) * cB.y));
  o.h[3] = __float22bfloat162_rn(make_float2(bf2f(in.s[6]) * cB.z, bf2f(in.s[7]) * cB.w));
  return o.u;
}

// ---------------------------------------------------------------------------
// prep (one-time): blocks [0,1152): x -> xb bf16 [b][ki] + xT bf16 [ki][b]
// (64x64 LDS transpose). blocks [1152,1296): W LDS-tiled -> Wt bf16 [ju][ki]
// (MFMA B layout) + Wr fp32 [ki][ju] (coalesced epilogue reads).
// ---------------------------------------------------------------------------
__global__ __launch_bounds__(256) void prep_kernel(
    const float* __restrict__ x, const float* __restrict__ W,
    unsigned short* __restrict__ xb, unsigned short* __restrict__ xT,
    unsigned short* __restrict__ Wt, float* __restrict__ Wr) {
  __shared__ float ts[32 * 322];    // 41.2 KB (x-part uses first 64*65)
  int id = blockIdx.x;
  int t = threadIdx.x;
  if (id < 1152) {
    int k0 = (id % 144) * 64;
    int b0 = (id / 144) * 64;
#pragma unroll
    for (int r = 0; r < 16; ++r) {
      int idx = t + 256 * r;
      int br = idx >> 6, kc = idx & 63;
      float v = x[(size_t)(b0 + br) * KI + k0 + kc];
      ts[br * 65 + kc] = v;
      xb[(size_t)(b0 + br) * KI + k0 + kc] = f2bf(v);
    }
    __syncthreads();
#pragma unroll
    for (int r = 0; r < 8; ++r) {
      int idx = t + 256 * r;            // 0..2047
      int kr = idx >> 5, bc = (idx & 31) * 2;
      unsigned lo = f2bf(ts[bc * 65 + kr]);
      unsigned hi = f2bf(ts[(bc + 1) * 65 + kr]);
      *(unsigned*)&xT[(size_t)(k0 + kr) * B + b0 + bc] = lo | (hi << 16);
    }
  } else {
    int wid = id - 1152;              // 0..143
    int i0 = (wid >> 2) * 32;         // 36 i-chunks
    int c0 = (wid & 3) * 320;         // 4 c-chunks of W's 1280-wide rows
#pragma unroll
    for (int r = 0; r < 20; ++r) {
      int q = t + 256 * r;            // < 5120 float2
      int il = q / 160, c = (q - il * 160) * 2;
      *(float2*)&ts[il * 322 + c] =
          *(const float2*)&W[(size_t)(i0 + il) * 1280 + c0 + c];
    }
    __syncthreads();
    {
      int il2 = (t & 15) * 2;
      for (int p = (t >> 4); p < 320; p += 16) {
        int c = c0 + p;
        int ju = c >> 3, k = c & 7;
        unsigned lo = f2bf(ts[il2 * 322 + p]);
        unsigned hi = f2bf(ts[(il2 + 1) * 322 + p]);
        *(unsigned*)&Wt[(size_t)ju * KI + k * IC + i0 + il2] = lo | (hi << 16);
      }
    }
    int ju0 = c0 >> 3;
    for (int q = t; q < 8 * 32 * 40; q += 256) {
      int k = q / 1280;
      int il = (q / 40) & 31;
      int jl = q - (q / 40) * 40;
      Wr[((size_t)k * IC + i0 + il) * JU + ju0 + jl] = ts[il * 322 + jl * 8 + k];
    }
  }
}

// ---------------------------------------------------------------------------
// s_gemm (MFMA, FUSED softmax-of-bij + c-scale, reg double-buffered):
// c[j,i] = exp(bij[j,i]) / sum_i exp(bij[j,i])  (denoms recomputed per block
// from the 46 KB bij buffer -- broadcast L2 read, no cross-block sync;
// bij==null => uniform 1/IC, iteration 1).
// sp[y][b][ju] = sum_{ki in chunk y} xb[b,ki] * (Wt[ju,ki] * c[j, i(ki)])
// Grid: (8 b-tiles of 64, NSPLIT) x 256.
// ---------------------------------------------------------------------------
__global__ __launch_bounds__(256) void s_gemm_mfma(
    const unsigned short* __restrict__ xb, const unsigned short* __restrict__ Wt,
    const float* __restrict__ bij, float* __restrict__ sp) {
  int b0 = blockIdx.x * 64;
  int kbase = blockIdx.y * KC;
  int i0 = kbase % IC;
  int t = threadIdx.x;
  int w = t >> 6, lane = t & 63, col = lane & 15, quad = lane >> 4;
  __shared__ unsigned short xs[64 * 40];    // pad 40: <=2-way (free)
  __shared__ unsigned short ms[160 * 40];
  __shared__ float cs[NU * KC];             // 11.5 KB
  __shared__ float sred[40];
  __shared__ float sinv[16];

  // ---- fused softmax: denominators (2 block syncs total) ----
  if (bij) {
#pragma unroll
    for (int j = 0; j < NU; ++j) {
      float sl = 0.0f;
#pragma unroll
      for (int r = 0; r < 5; ++r) {
        int i = t + 256 * r;
        if (i < IC) sl += __expf(bij[j * IC + i]);
      }
#pragma unroll
      for (int o = 32; o > 0; o >>= 1) sl += __shfl_xor(sl, o);
      if (lane == 0) sred[w * 10 + j] = sl;
    }
    __syncthreads();
    if (t < NU)
      sinv[t] = 1.0f / (sred[t] + sred[10 + t] + sred[20 + t] + sred[30 + t]);
    __syncthreads();
    for (int ch = t; ch < NU * KC; ch += 256) {
      int j = ch / KC;
      cs[ch] = __expf(bij[j * IC + i0 + (ch - j * KC)]) * sinv[j];
    }
  } else {
    for (int ch = t; ch < NU * KC; ch += 256) cs[ch] = 1.0f / (float)IC;
  }

  int xrow = t >> 2, xc = (t & 3) * 8;
  int mrow0 = t >> 2, mrow1 = (t + 256) >> 2, mrow2 = (t + 512) >> 2;
  int mc = (t & 3) * 8;
  int j0 = mrow0 >> 4, j1 = mrow1 >> 4, j2 = mrow2 >> 4;

  uint4 xv, m0, m1, m2;
  auto prefetch = [&](int k0) {
    xv = *(const uint4*)&xb[(size_t)(b0 + xrow) * KI + k0 + xc];
    m0 = *(const uint4*)&Wt[(size_t)mrow0 * KI + k0 + mc];
    m1 = *(const uint4*)&Wt[(size_t)mrow1 * KI + k0 + mc];
    if (t < 128) m2 = *(const uint4*)&Wt[(size_t)mrow2 * KI + k0 + mc];
  };
  auto commit = [&](int off) {
    *(uint4*)&xs[xrow * 40 + xc] = xv;
    float4 a0 = *(const float4*)&cs[j0 * KC + off + mc];
    float4 a1 = *(const float4*)&cs[j0 * KC + off + mc + 4];
    *(uint4*)&ms[mrow0 * 40 + mc] = scale8(m0, a0, a1);
    float4 b0c = *(const float4*)&cs[j1 * KC + off + mc];
    float4 b1c = *(const float4*)&cs[j1 * KC + off + mc + 4];
    *(uint4*)&ms[mrow1 * 40 + mc] = scale8(m1, b0c, b1c);
    if (t < 128) {
      float4 d0 = *(const float4*)&cs[j2 * KC + off + mc];
      float4 d1 = *(const float4*)&cs[j2 * KC + off + mc + 4];
      *(uint4*)&ms[mrow2 * 40 + mc] = scale8(m2, d0, d1);
    }
  };
  floatx4 acc[10];
#pragma unroll
  for (int jt = 0; jt < 10; ++jt) acc[jt] = (floatx4){0.f, 0.f, 0.f, 0.f};
  prefetch(kbase);
  __syncthreads();   // cs ready
  const int nsteps = KC >> 5;  // 9
  for (int s = 0; s < nsteps; ++s) {
    commit(s * 32);
    __syncthreads();
    if (s + 1 < nsteps) prefetch(kbase + (s + 1) * 32);
    bf16x8 a = *(bf16x8*)&xs[(w * 16 + col) * 40 + quad * 8];
#pragma unroll
    for (int jt = 0; jt < 10; ++jt) {
      bf16x8 bb = *(bf16x8*)&ms[(jt * 16 + col) * 40 + quad * 8];
      acc[jt] = __builtin_amdgcn_mfma_f32_16x16x32_bf16(a, bb, acc[jt], 0, 0, 0);
    }
    __syncthreads();
  }
#pragma unroll
  for (int jt = 0; jt < 10; ++jt)
#pragma unroll
    for (int r = 0; r < 4; ++r) {
      int b = b0 + w * 16 + quad * 4 + r;
      sp[((size_t)blockIdx.y * B + b) * JU + jt * 16 + col] = acc[jt][r];
    }
}

// ---------------------------------------------------------------------------
// squash: s[b][ju] = sum_ks sp; msq over j (axis=1 quirk, faithful);
// v -> vT bf16 [ju][b]; out fp32 on last iter. Block 0 zeroes bij for the
// FOLLOWING b_update (kernel boundary = ordering). Grid: 512 x 192.
// ---------------------------------------------------------------------------
__global__ __launch_bounds__(192) void squash_kernel(
    const float* __restrict__ sp, unsigned short* __restrict__ vT,
    float* __restrict__ out, float* __restrict__ bij) {
  int b = blockIdx.x;
  int t = threadIdx.x;
  if (b == 0) {
    for (int q = t; q < IC * NU; q += 192) bij[q] = 0.0f;
  }
  __shared__ float sv[JU];
  __shared__ float fac[US];
  float s = 0.0f;
  if (t < JU) {
#pragma unroll
    for (int k = 0; k < NSPLIT; ++k) s += sp[((size_t)k * B + b) * JU + t];
    sv[t] = s;
  }
  __syncthreads();
  if (t < US) {
    float m = 0.0f;
#pragma unroll
    for (int j = 0; j < NU; ++j) {
      float q = sv[j * US + t];
      m += q * q;
    }
    fac[t] = sqrtf(m) / (BETAC + m);
  }
  __syncthreads();
  if (t < JU) {
    float val = s * fac[t & 15];
    vT[(size_t)t * B + b] = f2bf(val);
    if (out) out[(size_t)b * JU + t] = val;
  }
}

// ---------------------------------------------------------------------------
// b_update (MFMA, dbuf): R[ki,ju] = sum_b xT[ki,b]*vT[ju,b] (K=b, split 2);
// bij[j][i] += (1/B) sum_u Wr[ki][ju]*R via fp32 atomicAdd (device-scope by
// default; NO fences -- visibility to the next kernel comes from the launch
// boundary). Grid: (144, 2) x 256.
// ---------------------------------------------------------------------------
__global__ __launch_bounds__(256) void b_update_mfma(
    const unsigned short* __restrict__ xT, const unsigned short* __restrict__ vT,
    const float* __restrict__ Wr, float* __restrict__ bij) {
  int k = blockIdx.x / 18;
  int i0 = (blockIdx.x - k * 18) * 64;
  int bs = blockIdx.y;
  size_t ki0 = (size_t)k * IC + i0;
  int t = threadIdx.x;
  int w = t >> 6, lane = t & 63, col = lane & 15, quad = lane >> 4;
  __shared__ unsigned short xs[64 * 40];
  __shared__ unsigned short vs[160 * 40];
  int xrow = t >> 2, xc = (t & 3) * 8;
  int mrow0 = t >> 2, mrow1 = (t + 256) >> 2, mrow2 = (t + 512) >> 2;
  int mc = (t & 3) * 8;
  uint4 xv, m0, m1, m2;
  auto prefetch = [&](int c0) {
    xv = *(const uint4*)&xT[(ki0 + xrow) * B + c0 + xc];
    m0 = *(const uint4*)&vT[(size_t)mrow0 * B + c0 + mc];
    m1 = *(const uint4*)&vT[(size_t)mrow1 * B + c0 + mc];
    if (t < 128) m2 = *(const uint4*)&vT[(size_t)mrow2 * B + c0 + mc];
  };
  auto commit = [&]() {
    *(uint4*)&xs[xrow * 40 + xc] = xv;
    *(uint4*)&vs[mrow0 * 40 + mc] = m0;
    *(uint4*)&vs[mrow1 * 40 + mc] = m1;
    if (t < 128) *(uint4*)&vs[mrow2 * 40 + mc] = m2;
  };
  floatx4 acc[10];
#pragma unroll
  for (int jt = 0; jt < 10; ++jt) acc[jt] = (floatx4){0.f, 0.f, 0.f, 0.f};
  prefetch(bs * 256);
  for (int s = 0; s < 8; ++s) {
    commit();
    __syncthreads();
    if (s < 7) prefetch(bs * 256 + (s + 1) * 32);
    bf16x8 a = *(bf16x8*)&xs[(w * 16 + col) * 40 + quad * 8];
#pragma unroll
    for (int jt = 0; jt < 10; ++jt) {
      bf16x8 bb = *(bf16x8*)&vs[(jt * 16 + col) * 40 + quad * 8];
      acc[jt] = __builtin_amdgcn_mfma_f32_16x16x32_bf16(a, bb, acc[jt], 0, 0, 0);
    }
    __syncthreads();
  }
#pragma unroll
  for (int jt = 0; jt < 10; ++jt) {
#pragma unroll
    for (int r = 0; r < 4; ++r) {
      int i = i0 + w * 16 + quad * 4 + r;
      float wv = Wr[((size_t)k * IC + i) * JU + jt * 16 + col];
      float pr = wv * acc[jt][r];
      pr += __shfl_xor(pr, 1);
      pr += __shfl_xor(pr, 2);
      pr += __shfl_xor(pr, 4);
      pr += __shfl_xor(pr, 8);
      if (col == 0)
        atomicAdd(&bij[jt * IC + i], pr * (1.0f / (float)B));
    }
  }
}

// ---------------------------------------------------------------------------
extern "C" void kernel_launch(void* const* d_in, const int* in_sizes, int n_in,
                              void* d_out, int out_size, void* d_ws,
                              size_t ws_size, hipStream_t stream) {
  const float* x = (const float*)d_in[0];   // (512, 8, 1152)
  const float* W = (const float*)d_in[1];   // (1152, 10, 16, 8)
  float* out = (float*)d_out;               // (512, 10, 16)

  // workspace layout (~38 MB; harness provides ~268 MB)
  char* pws = (char*)d_ws;
  float* bij = (float*)pws;                    pws += (size_t)NU * IC * 4;
  float* sp = (float*)pws;                     pws += (size_t)NSPLIT * B * JU * 4;
  float* Wr = (float*)pws;                     pws += (size_t)KI * JU * 4;
  unsigned short* xb = (unsigned short*)pws;   pws += (size_t)B * KI * 2;
  unsigned short* xT = (unsigned short*)pws;   pws += (size_t)KI * B * 2;
  unsigned short* Wt = (unsigned short*)pws;   pws += (size_t)JU * KI * 2;
  unsigned short* vT = (unsigned short*)pws;

  prep_kernel<<<1152 + 144, 256, 0, stream>>>(x, W, xb, xT, Wt, Wr);

  for (int it = 0; it < 3; ++it) {
    s_gemm_mfma<<<dim3(8, NSPLIT), 256, 0, stream>>>(
        xb, Wt, (it == 0) ? nullptr : bij, sp);
    squash_kernel<<<B, 192, 0, stream>>>(sp, vT, (it == 2) ? out : nullptr,
                                         bij);
    if (it < 2) {
      b_update_mfma<<<dim3(144, 2), 256, 0, stream>>>(xT, vT, Wr, bij);
    }
  }
}

// Round 9
// 176.884 us; speedup vs baseline: 1.4069x; 1.1373x over previous
//
#include <hip/hip_runtime.h>
#include <hip/hip_bf16.h>
#include <math.h>

#define B    512
#define INU  8
#define IC   1152
#define NU   10
#define US   16
#define JU   160            // NU*US
#define KI   9216           // INU*IC
#define BETAC 1.45f
#define NSPLIT 32
#define KC 288              // KI / NSPLIT; divides IC

typedef __attribute__((ext_vector_type(8))) __bf16 bf16x8;
typedef __attribute__((ext_vector_type(4))) float floatx4;

static __device__ __forceinline__ unsigned short f2bf(float f) {
  unsigned u = __builtin_bit_cast(unsigned, f);
  u = (u + 0x7fffu + ((u >> 16) & 1u)) >> 16;   // RNE
  return (unsigned short)u;
}
static __device__ __forceinline__ float bf2f(unsigned short h) {
  return __builtin_bit_cast(float, ((unsigned)h) << 16);
}
// 8 bf16 * 8 fp32 scale -> 8 bf16 (packed RNE converts)
static __device__ __forceinline__ uint4 scale8(uint4 wv, float4 cA, float4 cB) {
  union { uint4 u; unsigned short s[8]; } in;
  in.u = wv;
  union { uint4 u; __hip_bfloat162 h[4]; } o;
  o.h[0] = __float22bfloat162_rn(make_float2(bf2f(in.s[0]) * cA.x, bf2f(in.s[1]) * cA.y));
  o.h[1] = __float22bfloat162_rn(make_float2(bf2f(in.s[2]) * cA.z, bf2f(in.s[3]) * cA.w));
  o.h[2] = __float22bfloat162_rn(make_float2(bf2f(in.s[4]) * cB.x, bf2f(in.s[5]) * cB.y));
  o.h[3] = __float22bfloat162_rn(make_float2(bf2f(in.s[6]) * cB.z, bf2f(in.s[7]) * cB.w));
  return o.u;
}

// ---------------------------------------------------------------------------
// prep (one-time): blocks [0,1152): x -> xb bf16 [b][ki] + xT bf16 [ki][b]
// (64x64 LDS transpose). blocks [1152,1296): W LDS-tiled -> Wt bf16 [ju][ki]
// (MFMA B layout) + Wr fp32 [ki][ju] (coalesced epilogue reads). Block 1152
// inits cT = 1/IC (softmax of zero logits).
// ---------------------------------------------------------------------------
__global__ __launch_bounds__(256) void prep_kernel(
    const float* __restrict__ x, const float* __restrict__ W,
    unsigned short* __restrict__ xb, unsigned short* __restrict__ xT,
    unsigned short* __restrict__ Wt, float* __restrict__ Wr,
    float* __restrict__ cT) {
  __shared__ float ts[32 * 322];    // 41.2 KB (x-part uses first 64*65)
  int id = blockIdx.x;
  int t = threadIdx.x;
  if (id < 1152) {
    int k0 = (id % 144) * 64;
    int b0 = (id / 144) * 64;
#pragma unroll
    for (int r = 0; r < 16; ++r) {
      int idx = t + 256 * r;
      int br = idx >> 6, kc = idx & 63;
      float v = x[(size_t)(b0 + br) * KI + k0 + kc];
      ts[br * 65 + kc] = v;
      xb[(size_t)(b0 + br) * KI + k0 + kc] = f2bf(v);
    }
    __syncthreads();
#pragma unroll
    for (int r = 0; r < 8; ++r) {
      int idx = t + 256 * r;            // 0..2047
      int kr = idx >> 5, bc = (idx & 31) * 2;
      unsigned lo = f2bf(ts[bc * 65 + kr]);
      unsigned hi = f2bf(ts[(bc + 1) * 65 + kr]);
      *(unsigned*)&xT[(size_t)(k0 + kr) * B + b0 + bc] = lo | (hi << 16);
    }
  } else {
    int wid = id - 1152;              // 0..143
    int i0 = (wid >> 2) * 32;         // 36 i-chunks
    int c0 = (wid & 3) * 320;         // 4 c-chunks of W's 1280-wide rows
#pragma unroll
    for (int r = 0; r < 20; ++r) {
      int q = t + 256 * r;            // < 5120 float2
      int il = q / 160, c = (q - il * 160) * 2;
      *(float2*)&ts[il * 322 + c] =
          *(const float2*)&W[(size_t)(i0 + il) * 1280 + c0 + c];
    }
    __syncthreads();
    {
      int il2 = (t & 15) * 2;
      for (int p = (t >> 4); p < 320; p += 16) {
        int c = c0 + p;
        int ju = c >> 3, k = c & 7;
        unsigned lo = f2bf(ts[il2 * 322 + p]);
        unsigned hi = f2bf(ts[(il2 + 1) * 322 + p]);
        *(unsigned*)&Wt[(size_t)ju * KI + k * IC + i0 + il2] = lo | (hi << 16);
      }
    }
    int ju0 = c0 >> 3;
    for (int q = t; q < 8 * 32 * 40; q += 256) {
      int k = q / 1280;
      int il = (q / 40) & 31;
      int jl = q - (q / 40) * 40;
      Wr[((size_t)k * IC + i0 + il) * JU + ju0 + jl] = ts[il * 322 + jl * 8 + k];
    }
    if (id == 1152) {
      for (int q = t; q < IC * NU; q += 256) cT[q] = 1.0f / (float)IC;
    }
  }
}

// ---------------------------------------------------------------------------
// s_gemm (MFMA, fused c-scale from LDS, reg double-buffered):
// sp[y][b][ju] = sum_{ki in chunk y} xb[b,ki] * (Wt[ju,ki] * cT[j, i(ki)])
// Grid: (8 b-tiles of 64, NSPLIT) x 256.
// ---------------------------------------------------------------------------
__global__ __launch_bounds__(256) void s_gemm_mfma(
    const unsigned short* __restrict__ xb, const unsigned short* __restrict__ Wt,
    const float* __restrict__ cT, float* __restrict__ sp) {
  int b0 = blockIdx.x * 64;
  int kbase = blockIdx.y * KC;
  int i0 = kbase % IC;
  int t = threadIdx.x;
  int w = t >> 6, lane = t & 63, col = lane & 15, quad = lane >> 4;
  __shared__ unsigned short xs[64 * 40];    // pad 40: <=2-way (free)
  __shared__ unsigned short ms[160 * 40];
  __shared__ float cs[NU * KC];             // 11.5 KB

  int xrow = t >> 2, xc = (t & 3) * 8;
  int mrow0 = t >> 2, mrow1 = (t + 256) >> 2, mrow2 = (t + 512) >> 2;
  int mc = (t & 3) * 8;
  int j0 = mrow0 >> 4, j1 = mrow1 >> 4, j2 = mrow2 >> 4;

  for (int ch = t; ch < NU * KC; ch += 256) {
    int j = ch / KC;
    cs[ch] = cT[j * IC + i0 + (ch - j * KC)];
  }
  uint4 xv, m0, m1, m2;
  auto prefetch = [&](int k0) {
    xv = *(const uint4*)&xb[(size_t)(b0 + xrow) * KI + k0 + xc];
    m0 = *(const uint4*)&Wt[(size_t)mrow0 * KI + k0 + mc];
    m1 = *(const uint4*)&Wt[(size_t)mrow1 * KI + k0 + mc];
    if (t < 128) m2 = *(const uint4*)&Wt[(size_t)mrow2 * KI + k0 + mc];
  };
  auto commit = [&](int off) {
    *(uint4*)&xs[xrow * 40 + xc] = xv;
    float4 a0 = *(const float4*)&cs[j0 * KC + off + mc];
    float4 a1 = *(const float4*)&cs[j0 * KC + off + mc + 4];
    *(uint4*)&ms[mrow0 * 40 + mc] = scale8(m0, a0, a1);
    float4 b0c = *(const float4*)&cs[j1 * KC + off + mc];
    float4 b1c = *(const float4*)&cs[j1 * KC + off + mc + 4];
    *(uint4*)&ms[mrow1 * 40 + mc] = scale8(m1, b0c, b1c);
    if (t < 128) {
      float4 d0 = *(const float4*)&cs[j2 * KC + off + mc];
      float4 d1 = *(const float4*)&cs[j2 * KC + off + mc + 4];
      *(uint4*)&ms[mrow2 * 40 + mc] = scale8(m2, d0, d1);
    }
  };
  floatx4 acc[10];
#pragma unroll
  for (int jt = 0; jt < 10; ++jt) acc[jt] = (floatx4){0.f, 0.f, 0.f, 0.f};
  prefetch(kbase);
  __syncthreads();   // cs ready
  const int nsteps = KC >> 5;  // 9
  for (int s = 0; s < nsteps; ++s) {
    commit(s * 32);
    __syncthreads();
    if (s + 1 < nsteps) prefetch(kbase + (s + 1) * 32);
    bf16x8 a = *(bf16x8*)&xs[(w * 16 + col) * 40 + quad * 8];
#pragma unroll
    for (int jt = 0; jt < 10; ++jt) {
      bf16x8 bb = *(bf16x8*)&ms[(jt * 16 + col) * 40 + quad * 8];
      acc[jt] = __builtin_amdgcn_mfma_f32_16x16x32_bf16(a, bb, acc[jt], 0, 0, 0);
    }
    __syncthreads();
  }
#pragma unroll
  for (int jt = 0; jt < 10; ++jt)
#pragma unroll
    for (int r = 0; r < 4; ++r) {
      int b = b0 + w * 16 + quad * 4 + r;
      sp[((size_t)blockIdx.y * B + b) * JU + jt * 16 + col] = acc[jt][r];
    }
}

// ---------------------------------------------------------------------------
// squash: s[b][ju] = sum_ks sp; msq over j (axis=1 quirk, faithful);
// v -> vT bf16 [ju][b]; out fp32 on last iter. Grid: 512 x 192.
// ---------------------------------------------------------------------------
__global__ __launch_bounds__(192) void squash_kernel(
    const float* __restrict__ sp, unsigned short* __restrict__ vT,
    float* __restrict__ out) {
  int b = blockIdx.x;
  int t = threadIdx.x;
  __shared__ float sv[JU];
  __shared__ float fac[US];
  float s = 0.0f;
  if (t < JU) {
#pragma unroll
    for (int k = 0; k < NSPLIT; ++k) s += sp[((size_t)k * B + b) * JU + t];
    sv[t] = s;
  }
  __syncthreads();
  if (t < US) {
    float m = 0.0f;
#pragma unroll
    for (int j = 0; j < NU; ++j) {
      float q = sv[j * US + t];
      m += q * q;
    }
    fac[t] = sqrtf(m) / (BETAC + m);
  }
  __syncthreads();
  if (t < JU) {
    float val = s * fac[t & 15];
    vT[(size_t)t * B + b] = f2bf(val);
    if (out) out[(size_t)b * JU + t] = val;
  }
}

// ---------------------------------------------------------------------------
// b_update (MFMA, dbuf): R[ki,ju] = sum_b xT[ki,b]*vT[ju,b] (K=b, split 2);
// bp[p][j][i] = (1/B) sum_u Wr[ki][ju]*R (16-lane shfl reduce, u=lane&15).
// Wr layout makes the epilogue read fully coalesced. Grid: (144, 2) x 256.
// Deterministic slice writes, no atomics, no fences.
// ---------------------------------------------------------------------------
__global__ __launch_bounds__(256) void b_update_mfma(
    const unsigned short* __restrict__ xT, const unsigned short* __restrict__ vT,
    const float* __restrict__ Wr, float* __restrict__ bp) {
  int k = blockIdx.x / 18;
  int i0 = (blockIdx.x - k * 18) * 64;
  int bs = blockIdx.y;
  size_t ki0 = (size_t)k * IC + i0;
  int t = threadIdx.x;
  int w = t >> 6, lane = t & 63, col = lane & 15, quad = lane >> 4;
  __shared__ unsigned short xs[64 * 40];
  __shared__ unsigned short vs[160 * 40];
  int xrow = t >> 2, xc = (t & 3) * 8;
  int mrow0 = t >> 2, mrow1 = (t + 256) >> 2, mrow2 = (t + 512) >> 2;
  int mc = (t & 3) * 8;
  uint4 xv, m0, m1, m2;
  auto prefetch = [&](int c0) {
    xv = *(const uint4*)&xT[(ki0 + xrow) * B + c0 + xc];
    m0 = *(const uint4*)&vT[(size_t)mrow0 * B + c0 + mc];
    m1 = *(const uint4*)&vT[(size_t)mrow1 * B + c0 + mc];
    if (t < 128) m2 = *(const uint4*)&vT[(size_t)mrow2 * B + c0 + mc];
  };
  auto commit = [&]() {
    *(uint4*)&xs[xrow * 40 + xc] = xv;
    *(uint4*)&vs[mrow0 * 40 + mc] = m0;
    *(uint4*)&vs[mrow1 * 40 + mc] = m1;
    if (t < 128) *(uint4*)&vs[mrow2 * 40 + mc] = m2;
  };
  floatx4 acc[10];
#pragma unroll
  for (int jt = 0; jt < 10; ++jt) acc[jt] = (floatx4){0.f, 0.f, 0.f, 0.f};
  prefetch(bs * 256);
  for (int s = 0; s < 8; ++s) {
    commit();
    __syncthreads();
    if (s < 7) prefetch(bs * 256 + (s + 1) * 32);
    bf16x8 a = *(bf16x8*)&xs[(w * 16 + col) * 40 + quad * 8];
#pragma unroll
    for (int jt = 0; jt < 10; ++jt) {
      bf16x8 bb = *(bf16x8*)&vs[(jt * 16 + col) * 40 + quad * 8];
      acc[jt] = __builtin_amdgcn_mfma_f32_16x16x32_bf16(a, bb, acc[jt], 0, 0, 0);
    }
    __syncthreads();
  }
  int p = k * 2 + bs;
#pragma unroll
  for (int jt = 0; jt < 10; ++jt) {
#pragma unroll
    for (int r = 0; r < 4; ++r) {
      int i = i0 + w * 16 + quad * 4 + r;
      float wv = Wr[((size_t)k * IC + i) * JU + jt * 16 + col];
      float pr = wv * acc[jt][r];
      pr += __shfl_xor(pr, 1);
      pr += __shfl_xor(pr, 2);
      pr += __shfl_xor(pr, 4);
      pr += __shfl_xor(pr, 8);
      if (col == 0)
        bp[(size_t)p * (IC * NU) + jt * IC + i] = pr * (1.0f / (float)B);
    }
  }
}

// ---------------------------------------------------------------------------
// softmax over i (per j): bij[j][i] = sum_p bp[p][j][i]; cT[j][i] = softmax_i.
// Grid: 10 x 256. Coalesced over i.
// ---------------------------------------------------------------------------
__global__ __launch_bounds__(256) void softmax_c_kernel(
    const float* __restrict__ bp, float* __restrict__ cT) {
  int j = blockIdx.x;
  int t = threadIdx.x;
  __shared__ float bsum[IC];
  __shared__ float red[256];
  for (int i = t; i < IC; i += 256) {
    float s = 0.0f;
#pragma unroll
    for (int p = 0; p < 16; ++p) s += bp[(size_t)p * (IC * NU) + j * IC + i];
    bsum[i] = s;
  }
  __syncthreads();
  float m = -1e30f;
  for (int i = t; i < IC; i += 256) m = fmaxf(m, bsum[i]);
  red[t] = m;
  __syncthreads();
  for (int o = 128; o > 0; o >>= 1) {
    if (t < o) red[t] = fmaxf(red[t], red[t + o]);
    __syncthreads();
  }
  float mx = red[0];
  __syncthreads();
  float sm = 0.0f;
  for (int i = t; i < IC; i += 256) {
    float e = __expf(bsum[i] - mx);
    bsum[i] = e;
    sm += e;
  }
  red[t] = sm;
  __syncthreads();
  for (int o = 128; o > 0; o >>= 1) {
    if (t < o) red[t] += red[t + o];
    __syncthreads();
  }
  float inv = 1.0f / red[0];
  for (int i = t; i < IC; i += 256) cT[(size_t)j * IC + i] = bsum[i] * inv;
}

// ---------------------------------------------------------------------------
extern "C" void kernel_launch(void* const* d_in, const int* in_sizes, int n_in,
                              void* d_out, int out_size, void* d_ws,
                              size_t ws_size, hipStream_t stream) {
  const float* x = (const float*)d_in[0];   // (512, 8, 1152)
  const float* W = (const float*)d_in[1];   // (1152, 10, 16, 8)
  float* out = (float*)d_out;               // (512, 10, 16)

  // workspace layout (~39 MB; harness provides ~268 MB)
  char* pws = (char*)d_ws;
  float* cT = (float*)pws;                     pws += (size_t)NU * IC * 4;
  float* bp = (float*)pws;                     pws += (size_t)16 * IC * NU * 4;
  float* sp = (float*)pws;                     pws += (size_t)NSPLIT * B * JU * 4;
  float* Wr = (float*)pws;                     pws += (size_t)KI * JU * 4;
  unsigned short* xb = (unsigned short*)pws;   pws += (size_t)B * KI * 2;
  unsigned short* xT = (unsigned short*)pws;   pws += (size_t)KI * B * 2;
  unsigned short* Wt = (unsigned short*)pws;   pws += (size_t)JU * KI * 2;
  unsigned short* vT = (unsigned short*)pws;

  prep_kernel<<<1152 + 144, 256, 0, stream>>>(x, W, xb, xT, Wt, Wr, cT);

  for (int it = 0; it < 3; ++it) {
    s_gemm_mfma<<<dim3(8, NSPLIT), 256, 0, stream>>>(xb, Wt, cT, sp);
    squash_kernel<<<B, 192, 0, stream>>>(sp, vT, (it == 2) ? out : nullptr);
    if (it < 2) {
      b_update_mfma<<<dim3(144, 2), 256, 0, stream>>>(xT, vT, Wr, bp);
      softmax_c_kernel<<<NU, 256, 0, stream>>>(bp, cT);
    }
  }
}